// Round 15
// baseline (240.204 us; speedup 1.0000x reference)
//
#include <hip/hip_runtime.h>
#include <hip/hip_bf16.h>
#include <stdint.h>

// Problem constants
#define BB   2
#define CIN  32
#define COUT 16
#define DD   48
#define HIN  64
#define WIN  128
#define H2   128
#define W2   256

// Padded i8 activation tensor geometry (1 site = 32 i8 = 32 B)
#define WP   258                 // padded w stride (sites)
#define HP   130                 // padded rows per plane
#define PDP  (WP * HP)           // 33540: plane stride (sites)
#define PB   (PDP * 50)          // 1677000: batch stride (48 planes + 2 pad)
#define NSITES ((size_t)PB * BB) // 3,354,000 sites = 107.3 MB

#define NPAD_R1 134160           // dp in {0,49} full planes
#define NPAD_R2 49536            // dp 1..48, hp in {0,129}
#define NPAD_R3 24576            // dp 1..48, hp 1..128, wp in {0,257}
#define NPAD   (NPAD_R1 + NPAD_R2 + NPAD_R3)   // 208,272

typedef int v4i __attribute__((ext_vector_type(4)));

// ---------------------------------------------------------------------------
// prepB: blocks 0..15 build the i8 B-matrix (14 tap-pairs x 64 lanes x 16B,
// sign(W) with zero fill for the padded 28th tap) + alpha-folded BN scale/
// shift for co=blockIdx. Blocks >=16 zero the pad sites of xb.
// ---------------------------------------------------------------------------
__global__ __launch_bounds__(256) void ibc3d_prepB(
    const float* __restrict__ wgt, const float* __restrict__ gamma,
    const float* __restrict__ beta, const float* __restrict__ rmean,
    const float* __restrict__ rvar, uint8_t* __restrict__ Bmat,
    float* __restrict__ scale, float* __restrict__ shift,
    uint8_t* __restrict__ xb)
{
    __shared__ double sp[256];
    int bid = blockIdx.x, tid = threadIdx.x;

    if (bid < 16) {
        int co = bid;
        const float* wsl = wgt + (size_t)co * (CIN * 27);

        // B-matrix entries for the 4 lanes (per pair) whose l&15 == co
        if (tid < 56) {
            int p  = tid >> 2;            // pair [0,14)
            int lq = tid & 3;
            int l  = lq * 16 + co;        // lane
            int tap = (l >= 32) ? (2 * p + 1) : (2 * p);
            uint32_t dw[4] = {0u, 0u, 0u, 0u};
            if (tap < 27) {
                int cib = ((l >> 4) & 1) * 16;
                for (int jj = 0; jj < 16; ++jj) {
                    float w = wsl[(cib + jj) * 27 + tap];
                    uint32_t sb = w > 0.f ? 0x01u : (w < 0.f ? 0xFFu : 0x00u);
                    dw[jj >> 2] |= sb << ((jj & 3) * 8);
                }
            }
            *(uint4*)(Bmat + ((size_t)p * 64 + l) * 16) =
                make_uint4(dw[0], dw[1], dw[2], dw[3]);
        }

        // alpha = mean|W| (fp64 block reduce)
        double s = 0.0;
        for (int i = tid; i < CIN * 27; i += 256) s += fabs((double)wsl[i]);
        sp[tid] = s;
        __syncthreads();
#pragma unroll
        for (int st = 128; st > 0; st >>= 1) {
            if (tid < st) sp[tid] += sp[tid + st];
            __syncthreads();
        }
        if (tid == 0) {
            float alpha = (float)(sp[0] / (double)(CIN * 27));
            float inv = gamma[co] / sqrtf(rvar[co] + 1e-5f);
            scale[co] = alpha * inv;
            shift[co] = beta[co] - rmean[co] * inv;
        }
    } else {
        // zero pad sites
        int i = (bid - 16) * 256 + tid;
        if (i >= NPAD) return;
        size_t site;
        if (i < NPAD_R1) {
            int bq = i / 67080; int m = i - bq * 67080;      // 2*130*258
            int ds = m / PDP;   int r2 = m - ds * PDP;
            int hp = r2 / WP,   wp = r2 % WP;
            site = (size_t)bq * PB + (size_t)(ds ? 49 : 0) * PDP + hp * WP + wp;
        } else if (i < NPAD_R1 + NPAD_R2) {
            int i2 = i - NPAD_R1;
            int bq = i2 / 24768; int m = i2 - bq * 24768;    // 48*2*258
            int dp = 1 + m / 516; int r2 = m - (dp - 1) * 516;
            int hp = (r2 / WP) ? 129 : 0; int wp = r2 % WP;
            site = (size_t)bq * PB + (size_t)dp * PDP + hp * WP + wp;
        } else {
            int i3 = i - NPAD_R1 - NPAD_R2;
            int bq = i3 / 12288; int m = i3 - bq * 12288;    // 48*128*2
            int dp = 1 + m / 256; int r2 = m & 255;
            int hp = 1 + (r2 >> 1); int wp = (r2 & 1) ? 257 : 0;
            site = (size_t)bq * PB + (size_t)dp * PDP + hp * WP + wp;
        }
        uint8_t* pz = xb + site * 32;
        *(uint4*)pz        = make_uint4(0u, 0u, 0u, 0u);
        *(uint4*)(pz + 16) = make_uint4(0u, 0u, 0u, 0u);
    }
}

// ---------------------------------------------------------------------------
// packi8: thread = (plane, h2, 8-site group j, ci-quarter q). packr8-verified
// upsample math (fp32 + fp64 fallback when |v|<1e-5); writes 8 sites x 8 ci
// as +1/-1 i8 into the PADDED [site][ci] tensor.
// ---------------------------------------------------------------------------
__global__ __launch_bounds__(256) void ibc3d_packi8(
    const float* __restrict__ x, uint8_t* __restrict__ xb)
{
    int idx = blockIdx.x * 256 + threadIdx.x;   // < 96*128*32*4 = 1,572,864
    int j  = idx & 31;
    int q  = (idx >> 5) & 3;
    int h2 = (idx >> 7) & 127;
    int pl = idx >> 14;
    int d = pl % DD, b = pl / DD;

    int m = h2 >> 1, qq = h2 & 1;
    int rT = qq ? m : (m > 0 ? m - 1 : 0);
    int rB = qq ? (m < HIN - 1 ? m + 1 : HIN - 1) : m;
    float wT = qq ? 0.75f : 0.25f;
    float wB = 1.0f - wT;

    int c0 = 4 * j;
    int cl = c0 >= 2 ? c0 - 2 : 0;
    int cr = (c0 + 4 <= WIN - 2) ? c0 + 4 : WIN - 2;

    const float* xp = x + ((size_t)b * CIN * DD + d) * (HIN * WIN);
    int oT = rT * WIN, oB2 = rB * WIN;

    uint32_t d0[8], d1[8];
#pragma unroll
    for (int k = 0; k < 8; ++k) { d0[k] = 0u; d1[k] = 0u; }

    for (int c = 0; c < 8; ++c) {
        int ci = q * 8 + c;
        const float* xc = xp + (size_t)ci * (DD * HIN * WIN);
        float cT[6], cB[6];
        {
            const float* rowT = xc + oT;
            float2 L = *(const float2*)(rowT + cl);
            float4 M = *(const float4*)(rowT + c0);
            float2 R = *(const float2*)(rowT + cr);
            cT[0] = (j > 0)  ? L.y : L.x;
            cT[1] = M.x; cT[2] = M.y; cT[3] = M.z; cT[4] = M.w;
            cT[5] = (j < 31) ? R.x : R.y;
        }
        {
            const float* rowB = xc + oB2;
            float2 L = *(const float2*)(rowB + cl);
            float4 M = *(const float4*)(rowB + c0);
            float2 R = *(const float2*)(rowB + cr);
            cB[0] = (j > 0)  ? L.y : L.x;
            cB[1] = M.x; cB[2] = M.y; cB[3] = M.z; cB[4] = M.w;
            cB[5] = (j < 31) ? R.x : R.y;
        }

        float v[8];
#pragma unroll
        for (int t = 0; t < 4; ++t) {
            float uT0 = 0.25f * cT[t]     + 0.75f * cT[t + 1];
            float uT1 = 0.75f * cT[t + 1] + 0.25f * cT[t + 2];
            float uB0 = 0.25f * cB[t]     + 0.75f * cB[t + 1];
            float uB1 = 0.75f * cB[t + 1] + 0.25f * cB[t + 2];
            v[2 * t]     = wT * uT0 + wB * uB0;
            v[2 * t + 1] = wT * uT1 + wB * uB1;
        }

        float amin = 3.4e38f;
#pragma unroll
        for (int k = 0; k < 8; ++k) amin = fminf(amin, fabsf(v[k]));

        uint32_t sb[8];
        if (__builtin_expect(amin < 1e-5f, 0)) {
            double dwT = (double)wT, dwB = 1.0 - (double)wT;
#pragma unroll
            for (int t = 0; t < 4; ++t) {
                double eT0 = 0.25 * (double)cT[t]     + 0.75 * (double)cT[t + 1];
                double eT1 = 0.75 * (double)cT[t + 1] + 0.25 * (double)cT[t + 2];
                double eB0 = 0.25 * (double)cB[t]     + 0.75 * (double)cB[t + 1];
                double eB1 = 0.75 * (double)cB[t + 1] + 0.25 * (double)cB[t + 2];
                sb[2 * t]     = (dwT * eT0 + dwB * eB0) >= 0.0 ? 0x01u : 0xFFu;
                sb[2 * t + 1] = (dwT * eT1 + dwB * eB1) >= 0.0 ? 0x01u : 0xFFu;
            }
        } else {
#pragma unroll
            for (int k = 0; k < 8; ++k) sb[k] = v[k] >= 0.f ? 0x01u : 0xFFu;
        }

        if (c < 4) {
#pragma unroll
            for (int k = 0; k < 8; ++k) d0[k] |= sb[k] << (c * 8);
        } else {
#pragma unroll
            for (int k = 0; k < 8; ++k) d1[k] |= sb[k] << ((c - 4) * 8);
        }
    }

    size_t base = (size_t)b * PB + (size_t)(d + 1) * PDP +
                  (size_t)(h2 + 1) * WP + 1 + j * 8;
#pragma unroll
    for (int k = 0; k < 8; ++k)
        *(uint2*)(xb + (base + k) * 32 + q * 8) = make_uint2(d0[k], d1[k]);
}

// ---------------------------------------------------------------------------
// convmf: i8 MFMA conv. Block = one (plane,h2) row: 4 waves x 4 groups of 16
// sites. Per tap-pair p: A = 16 sites x 64 k (2 taps x 32 ci) loaded direct
// from the padded tensor (lane l: site l&15 of tap (l<32?2p:2p+1), 16B ci
// slice ((l>>4)&1)*16); B resident in VGPRs. K-placement identical on A and
// B sides => dot invariant to K-order. C: col(co)=l&15, row(site)=(l>>4)*4+r
// [guide-verified, dtype-independent]. Pads are zero => exact conv padding.
// ---------------------------------------------------------------------------
__global__ __launch_bounds__(256) void ibc3d_convmf(
    const uint8_t* __restrict__ xb, const uint8_t* __restrict__ Bmat,
    const float* __restrict__ scaleg, const float* __restrict__ shiftg,
    float* __restrict__ out)
{
    int bid = blockIdx.x;            // 96*128
    int h2 = bid & 127;
    int pl = bid >> 7;
    int b = pl / DD, d = pl % DD;
    int tid = threadIdx.x;
    int l = tid & 63, wid = tid >> 6;
    int ls = l & 15;
    bool hi = l >= 32;
    int ci0 = ((l >> 4) & 1) * 16;

    v4i bf[14];
#pragma unroll
    for (int p = 0; p < 14; ++p)
        bf[p] = *(const v4i*)(Bmat + ((size_t)p * 64 + l) * 16);

    size_t base = (size_t)b * PB + (size_t)(d + 1) * PDP +
                  (size_t)(h2 + 1) * WP + 1;

    v4i acc[4];
#pragma unroll
    for (int g = 0; g < 4; ++g) acc[g] = (v4i){0, 0, 0, 0};

#pragma unroll
    for (int p = 0; p < 14; ++p) {
        const int t0 = 2 * p;
        const int t1 = (2 * p + 1 < 27) ? (2 * p + 1) : 26;   // addr only; B=0
        const int off0 = (t0 / 9 - 1) * PDP + ((t0 % 9) / 3 - 1) * WP + (t0 % 3 - 1);
        const int off1 = (t1 / 9 - 1) * PDP + ((t1 % 9) / 3 - 1) * WP + (t1 % 3 - 1);
        int offs = hi ? off1 : off0;
#pragma unroll
        for (int g = 0; g < 4; ++g) {
            size_t s = base + (size_t)((wid * 4 + g) * 16 + ls);
            const v4i a = *(const v4i*)(xb + (s + offs) * 32 + ci0);
            acc[g] = __builtin_amdgcn_mfma_i32_16x16x64_i8(a, bf[p], acc[g], 0, 0, 0);
        }
    }

    int co = ls;
    float sc = scaleg[co], sh = shiftg[co];
    size_t obase = (((size_t)(b * COUT + co) * DD + d) * H2 + h2) * W2;
#pragma unroll
    for (int g = 0; g < 4; ++g) {
        int grp = wid * 4 + g;
#pragma unroll
        for (int r = 0; r < 4; ++r) {
            int w2 = grp * 16 + ((l >> 4) << 2) + r;
            float y = (float)acc[g][r] * sc + sh;
            out[obase + w2] = y > 0.f ? y : 0.f;
        }
    }
}

// ---------------------------------------------------------------------------
// fused zero-scratch fallback (unchanged from passing rounds).
// ---------------------------------------------------------------------------
__device__ __forceinline__ uint32_t pack_word(const float* __restrict__ x,
                                              int b, int d, int h2, int w2)
{
    int m = h2 >> 1, dh = h2 & 1;
    int n = w2 >> 1, dwp = w2 & 1;
    int rA = m + dh - 1;
    int rB = rA + 1;
    double wA = dh ? 0.75 : 0.25;
    double wB = 1.0 - wA;
    rA = rA < 0 ? 0 : rA;
    rB = rB > (HIN - 1) ? (HIN - 1) : rB;
    int cA = n + dwp - 1;
    int cB = cA + 1;
    double wC = dwp ? 0.75 : 0.25;
    double wD = 1.0 - wC;
    cA = cA < 0 ? 0 : cA;
    cB = cB > (WIN - 1) ? (WIN - 1) : cB;

    const float* xp = x + ((size_t)b * CIN * DD + d) * (HIN * WIN);
    int oA = rA * WIN, oB = rB * WIN;
    uint32_t word = 0;
    for (int ci = 0; ci < CIN; ++ci) {
        const float* xc = xp + (size_t)ci * (DD * HIN * WIN);
        float a0 = xc[oA + cA], a1 = xc[oA + cB];
        float b0 = xc[oB + cA], b1 = xc[oB + cB];
        double t0 = wA * (double)a0 + wB * (double)b0;
        double t1 = wA * (double)a1 + wB * (double)b1;
        double v  = wC * t0 + wD * t1;
        word |= (v >= 0.0 ? 1u : 0u) << ci;
    }
    return word;
}

__global__ __launch_bounds__(256) void ibc3d_fused(
    const float* __restrict__ x, const float* __restrict__ wgt,
    const float* __restrict__ gamma, const float* __restrict__ beta,
    const float* __restrict__ rmean, const float* __restrict__ rvar,
    float* __restrict__ out)
{
    __shared__ uint32_t sbw[27 * 16];
    __shared__ float sscale[16];
    __shared__ float sshift[16];
    __shared__ uint32_t sw[3][10][264];

    int tid = threadIdx.x;
    for (int t = tid; t < 27 * 16; t += 256) {
        int tap = t >> 4, co = t & 15;
        uint32_t word = 0;
        for (int ci = 0; ci < CIN; ++ci) {
            float v = wgt[(co * CIN + ci) * 27 + tap];
            word |= (v > 0.0f ? 1u : 0u) << ci;
        }
        sbw[t] = word;
    }
    if (tid < 16) {
        int co = tid;
        double s = 0.0;
        for (int i = 0; i < CIN * 27; ++i)
            s += fabs((double)wgt[co * CIN * 27 + i]);
        float alpha = (float)(s / (double)(CIN * 27));
        float inv = gamma[co] / sqrtf(rvar[co] + 1e-5f);
        sscale[co] = alpha * inv;
        sshift[co] = beta[co] - rmean[co] * inv;
    }

    int bid = blockIdx.x;
    int hq  = bid & 15;
    int r   = bid >> 4;
    int b   = r / DD;
    int d   = r % DD;
    int h2base = hq * 8;

    for (int i = tid; i < 3 * 10 * 258; i += 256) {
        int kd  = i / 2580;
        int rem = i - kd * 2580;
        int ri  = rem / 258;
        int ciw = rem - ri * 258;
        int dd = d + kd - 1;
        int h2 = h2base - 1 + ri;
        int w2 = ciw - 1;
        uint32_t word = 0;
        if (dd >= 0 && dd < DD && h2 >= 0 && h2 < H2 && w2 >= 0 && w2 < W2)
            word = pack_word(x, b, dd, h2, w2);
        sw[kd][ri][ciw] = word;
    }
    __syncthreads();

    int w2 = tid;
    for (int p = 0; p < 8; ++p) {
        int h2 = h2base + p;
        int acc[16];
#pragma unroll
        for (int c = 0; c < 16; ++c) acc[c] = 0;
        int nv = 0;
        for (int kd = 0; kd < 3; ++kd) {
            int dd = d + kd - 1;
            if (dd < 0 || dd >= DD) continue;
            for (int kh = 0; kh < 3; ++kh) {
                int hh = h2 + kh - 1;
                if (hh < 0 || hh >= H2) continue;
                for (int kw = 0; kw < 3; ++kw) {
                    int ww = w2 + kw - 1;
                    if (ww < 0 || ww >= W2) continue;
                    uint32_t word = sw[kd][p + kh][w2 + kw];
                    nv += 1;
                    int tap = kd * 9 + kh * 3 + kw;
#pragma unroll
                    for (int co = 0; co < 16; ++co)
                        acc[co] += __popc(word ^ sbw[tap * 16 + co]);
                }
            }
        }
        float base = 32.0f * (float)nv;
#pragma unroll
        for (int co = 0; co < 16; ++co) {
            float y = (base - 2.0f * (float)acc[co]) * sscale[co] + sshift[co];
            y = y > 0.0f ? y : 0.0f;
            size_t oidx = (((size_t)(b * COUT + co) * DD + d) * H2 + h2) * W2 + w2;
            out[oidx] = y;
        }
    }
}

extern "C" void kernel_launch(void* const* d_in, const int* in_sizes, int n_in,
                              void* d_out, int out_size, void* d_ws, size_t ws_size,
                              hipStream_t stream)
{
    (void)in_sizes; (void)n_in; (void)out_size;
    const float* x     = (const float*)d_in[0];
    const float* wgt   = (const float*)d_in[1];
    const float* gamma = (const float*)d_in[2];
    const float* beta  = (const float*)d_in[3];
    const float* rmean = (const float*)d_in[4];
    const float* rvar  = (const float*)d_in[5];
    float* out = (float*)d_out;

    const size_t XBOFF = 32768;
    const size_t need = XBOFF + NSITES * 32;   // ~107.4 MB

    if (d_ws != nullptr && ws_size >= need) {
        uint8_t* ws    = (uint8_t*)d_ws;
        uint8_t* Bmat  = ws;                    // 14 KB
        float*   scale = (float*)(ws + 16384);
        float*   shift = (float*)(ws + 16448);
        uint8_t* xb    = ws + XBOFF;

        int zblocks = 16 + (NPAD + 255) / 256;  // 830
        ibc3d_prepB<<<zblocks, 256, 0, stream>>>(wgt, gamma, beta, rmean, rvar,
                                                 Bmat, scale, shift, xb);
        ibc3d_packi8<<<6144, 256, 0, stream>>>(x, xb);
        ibc3d_convmf<<<BB * DD * H2, 256, 0, stream>>>(xb, Bmat, scale, shift, out);
    } else {
        ibc3d_fused<<<BB * DD * (H2 / 8), 256, 0, stream>>>(
            x, wgt, gamma, beta, rmean, rvar, out);
    }
}